// Round 9
// baseline (126.674 us; speedup 1.0000x reference)
//
#include <hip/hip_runtime.h>

#define BS 4
#define DM 1024
#define LL 2048
#define NS 64
#define NCH 16        // chunks per d-row (one per lane quad)
#define TCL 128       // chunk length = LL/NCH
#define DPB 4         // d-rows per block (one per wave, 256-thread blocks)
#define NSG 16        // states per lane (grp = lane&3 picks quarter)

// DPP quad_perm cross-lane adds: pure VALU, zero DS-pipe traffic.
__device__ __forceinline__ float dpp_add_xor1(float v) {  // lane ^ 1 within quad
    int r = __builtin_amdgcn_update_dpp(0, __float_as_int(v), 0xB1, 0xF, 0xF, true);
    return v + __int_as_float(r);
}
__device__ __forceinline__ float dpp_add_xor2(float v) {  // lane ^ 2 within quad
    int r = __builtin_amdgcn_update_dpp(0, __float_as_int(v), 0x4E, 0xF, 0xF, true);
    return v + __int_as_float(r);
}

// No LDS at all: u read from global (L3/L2-resident, quad-broadcast pattern),
// y stored directly. Occupancy VGPR-bound only -> target 8 waves/SIMD.
__global__ __launch_bounds__(256, 6) void ssm_fused(const float* __restrict__ u,
                                                    const float* __restrict__ A,
                                                    const float* __restrict__ Bv,
                                                    const float* __restrict__ Cv,
                                                    float* __restrict__ y) {
    const int tid  = threadIdx.x;
    const int bx   = blockIdx.x;           // 1024 blocks = BS * DM/DPB
    const int b    = bx >> 8;
    const int d    = (bx & 255) * DPB + (tid >> 6);
    const int lane = tid & 63;
    const int ch   = lane >> 2;            // chunk 0..15
    const int grp  = lane & 3;             // state quarter
    const int ib   = NSG * grp;

    const float* urow = u + (size_t)(b * DM + d) * LL + ch * TCL;

    // a params: divergent per-grp addresses -> VGPR-resident
    float a[NSG];
#pragma unroll
    for (int j = 0; j < NSG; ++j) a[j] = A[(ib + j) * (NS + 1)];

    // ---- phase A: chunk-local end states (zero init), float4 global reads ----
    float g[NSG];
#pragma unroll
    for (int j = 0; j < NSG; ++j) g[j] = 0.f;
#pragma unroll 2
    for (int tq = 0; tq < TCL / 4; ++tq) {
        const float4 u4 = *reinterpret_cast<const float4*>(urow + tq * 4);
        const float* up = reinterpret_cast<const float*>(&u4);
#pragma unroll
        for (int e = 0; e < 4; ++e) {
            const float uv = up[e];
#pragma unroll
            for (int j = 0; j < NSG; ++j) g[j] = fmaf(a[j], g[j], uv);
        }
    }

    // ---- in-wave combine: inclusive Hillis-Steele scan over 16 chunks, then shift ----
    {
        float m[NSG];
#pragma unroll
        for (int j = 0; j < NSG; ++j) {
            float x = a[j];
#pragma unroll
            for (int q = 0; q < 7; ++q) x = x * x;   // a^128
            m[j] = x;
        }
#pragma unroll
        for (int k = 0; k < 4; ++k) {
            const int off = 4 << k;                  // 2^k chunks = 4*2^k lanes
            const int src = (lane >= off) ? (lane - off) : 0;
            const bool ok = lane >= off;
#pragma unroll
            for (int j = 0; j < NSG; ++j) {
                const float h = __shfl(g[j], src, 64);
                g[j] = fmaf(ok ? m[j] : 0.0f, h, g[j]);
                m[j] = m[j] * m[j];
            }
        }
        const int src = (lane >= 4) ? (lane - 4) : 0;
#pragma unroll
        for (int j = 0; j < NSG; ++j) {
            const float h = __shfl(g[j], src, 64);
            g[j] = (ch == 0) ? 0.0f : h;             // exclusive: true chunk-initial state
        }
    }

    // w params loaded AFTER combine: keeps peak live-set < 64 regs (8-wave budget)
    float w[NSG];
#pragma unroll
    for (int j = 0; j < NSG; ++j) w[j] = Bv[ib + j] * Cv[ib + j];

    float* yrow = y + (size_t)(b * DM + d) * LL + ch * TCL;

    // ---- phase B: rescan with true init; DPP quad-reduce; direct float4 y stores ----
#pragma unroll 2
    for (int tq = 0; tq < TCL / 4; ++tq) {
        const float4 u4 = *reinterpret_cast<const float4*>(urow + tq * 4);
        const float* up = reinterpret_cast<const float*>(&u4);
        float y4[4];
#pragma unroll
        for (int e = 0; e < 4; ++e) {
            const float uv = up[e];
            float y0 = 0.f, y1 = 0.f, y2 = 0.f, y3 = 0.f;
#pragma unroll
            for (int j = 0; j < NSG; j += 4) {
                g[j + 0] = fmaf(a[j + 0], g[j + 0], uv); y0 = fmaf(w[j + 0], g[j + 0], y0);
                g[j + 1] = fmaf(a[j + 1], g[j + 1], uv); y1 = fmaf(w[j + 1], g[j + 1], y1);
                g[j + 2] = fmaf(a[j + 2], g[j + 2], uv); y2 = fmaf(w[j + 2], g[j + 2], y2);
                g[j + 3] = fmaf(a[j + 3], g[j + 3], uv); y3 = fmaf(w[j + 3], g[j + 3], y3);
            }
            float yp = (y0 + y1) + (y2 + y3);
            yp = dpp_add_xor1(yp);               // quad reduce across 4 state-quarters
            yp = dpp_add_xor2(yp);
            y4[e] = yp;
        }
        if (grp == 0)
            *reinterpret_cast<float4*>(yrow + tq * 4) =
                make_float4(y4[0], y4[1], y4[2], y4[3]);
    }
}

extern "C" void kernel_launch(void* const* d_in, const int* in_sizes, int n_in,
                              void* d_out, int out_size, void* d_ws, size_t ws_size,
                              hipStream_t stream) {
    const float* u  = (const float*)d_in[0];
    const float* A  = (const float*)d_in[1];
    const float* Bv = (const float*)d_in[2];
    const float* Cv = (const float*)d_in[3];
    float* y = (float*)d_out;

    ssm_fused<<<BS * (DM / DPB), 256, 0, stream>>>(u, A, Bv, Cv, y);
}

// Round 10
// 66.544 us; speedup vs baseline: 1.9036x; 1.9036x over previous
//
#include <hip/hip_runtime.h>

#define BS 4
#define DM 1024
#define LL 2048
#define NS 64
#define NCH 8         // chunks per half-row (per wave)
#define TCL 128       // chunk length
#define CPAD 132      // padded chunk stride (dwords): 16B-aligned, conflict-free patterns
#define RSTR (16 * CPAD)   // dwords per d-row (16 global chunks)
#define NSG 8         // states per lane (grp = lane&7)

// DPP cross-lane adds: pure VALU, zero DS-pipe traffic.
__device__ __forceinline__ float dpp_xor1(float v) {   // lane^1 within quad
    int r = __builtin_amdgcn_update_dpp(0, __float_as_int(v), 0xB1, 0xF, 0xF, true);
    return v + __int_as_float(r);
}
__device__ __forceinline__ float dpp_xor2(float v) {   // lane^2 within quad
    int r = __builtin_amdgcn_update_dpp(0, __float_as_int(v), 0x4E, 0xF, 0xF, true);
    return v + __int_as_float(r);
}
__device__ __forceinline__ float dpp_mir8(float v) {   // row_half_mirror: i -> 7-i per 8 lanes
    int r = __builtin_amdgcn_update_dpp(0, __float_as_int(v), 0x141, 0xF, 0xF, true);
    return v + __int_as_float(r);
}

// One kernel: 2048 blocks x 256 thr. Block = 2 d-rows; each d-row split over
// 2 waves (8 chunks x 128 each); halves bridged via 64-float LDS exchange.
__global__ __launch_bounds__(256, 4) void ssm_fused(const float* __restrict__ u,
                                                    const float* __restrict__ A,
                                                    const float* __restrict__ Bv,
                                                    const float* __restrict__ Cv,
                                                    float* __restrict__ y) {
    __shared__ float uS[2 * RSTR];     // 16896 B: 2 d-rows x 2048 (chunk-padded)
    __shared__ float hb[2][NS];        // half-boundary states per d-row (512 B)

    const int tid  = threadIdx.x;
    const int bx   = blockIdx.x;       // 2048 = BS * DM/2
    const int b    = bx >> 9;
    const int dp   = bx & 511;         // d-row pair
    const int wid  = tid >> 6;
    const int row  = wid >> 1;         // d-row within block
    const int half = wid & 1;          // L-half owned by this wave
    const int lane = tid & 63;
    const int ch   = lane >> 3;        // chunk 0..7 within half
    const int grp  = lane & 7;         // state octet
    const int ib   = NSG * grp;

    // ---- stage 2 d-rows x 2048 floats, float4 both sides ----
    {
        const float* ubase = u + ((size_t)b * DM + dp * 2) * LL;
#pragma unroll
        for (int k = 0; k < 4; ++k) {
            const int idx = tid + k * 256;          // 1024 float4 slots
            const int r   = idx >> 9;
            const int t4  = (idx & 511) * 4;
            const int c   = t4 >> 7;
            const int tin = t4 & 127;
            const float4 v = *reinterpret_cast<const float4*>(ubase + (size_t)r * LL + t4);
            *reinterpret_cast<float4*>(&uS[r * RSTR + c * CPAD + tin]) = v;
        }
    }

    // ---- params: divergent per-grp addresses -> VGPR-resident (a8 only for now) ----
    float a[NSG];
#pragma unroll
    for (int j = 0; j < NSG; ++j) a[j] = A[(ib + j) * (NS + 1)];

    __syncthreads();

    const int cb = row * RSTR + (half * NCH + ch) * CPAD;   // my chunk base (dwords)

    // ---- phase A: chunk-local end states (zero init) ----
    float g[NSG];
#pragma unroll
    for (int j = 0; j < NSG; ++j) g[j] = 0.f;
    for (int tq = 0; tq < TCL / 4; ++tq) {
        const float4 u4 = *reinterpret_cast<const float4*>(&uS[cb + tq * 4]);
        const float* up = reinterpret_cast<const float*>(&u4);
#pragma unroll
        for (int e = 0; e < 4; ++e) {
            const float uv = up[e];
#pragma unroll
            for (int j = 0; j < NSG; ++j) g[j] = fmaf(a[j], g[j], uv);
        }
    }

    // ---- in-wave inclusive scan over 8 chunks; build f = (a^128)^ch on the side ----
    float f[NSG];
    {
        float m[NSG];
#pragma unroll
        for (int j = 0; j < NSG; ++j) {
            float x = a[j];
#pragma unroll
            for (int q = 0; q < 7; ++q) x = x * x;   // a^128
            m[j] = x;
            f[j] = 1.f;
        }
#pragma unroll
        for (int k = 0; k < 3; ++k) {
            const int off  = 8 << k;                 // 1,2,4 chunks = 8,16,32 lanes
            const int src  = (lane >= off) ? (lane - off) : 0;
            const bool ok  = lane >= off;
            const bool bit = (ch >> k) & 1;
#pragma unroll
            for (int j = 0; j < NSG; ++j) {
                const float h = __shfl(g[j], src, 64);
                g[j] = fmaf(ok ? m[j] : 0.0f, h, g[j]);
                f[j] = bit ? f[j] * m[j] : f[j];
                m[j] = m[j] * m[j];
            }
        }
    }

    // ---- export half-0 inclusive end state (pre-shift), then exclusive shift ----
    if (half == 0 && ch == 7) {
#pragma unroll
        for (int j = 0; j < NSG; ++j) hb[row][ib + j] = g[j];
    }
    {
        const int src = (lane >= 8) ? (lane - 8) : 0;
#pragma unroll
        for (int j = 0; j < NSG; ++j) {
            const float h = __shfl(g[j], src, 64);
            g[j] = (ch == 0) ? 0.0f : h;             // exclusive chunk-initial state
        }
    }

    __syncthreads();

    // ---- half-1: fold in half-0's end state: g += (a^128)^ch * H0end ----
    if (half == 1) {
#pragma unroll
        for (int j = 0; j < NSG; ++j) g[j] = fmaf(f[j], hb[row][ib + j], g[j]);
    }

    // w loaded late: keeps peak live-set small through the scan
    float w[NSG];
#pragma unroll
    for (int j = 0; j < NSG; ++j) w[j] = Bv[ib + j] * Cv[ib + j];

    // ---- phase B: rescan with true init; 8-lane DPP reduce; y -> uS in place ----
    for (int tq = 0; tq < TCL / 4; ++tq) {
        const float4 u4 = *reinterpret_cast<const float4*>(&uS[cb + tq * 4]);
        const float* up = reinterpret_cast<const float*>(&u4);
        float y4[4];
#pragma unroll
        for (int e = 0; e < 4; ++e) {
            const float uv = up[e];
            float y0 = 0.f, y1 = 0.f;
#pragma unroll
            for (int j = 0; j < NSG; j += 2) {
                g[j + 0] = fmaf(a[j + 0], g[j + 0], uv); y0 = fmaf(w[j + 0], g[j + 0], y0);
                g[j + 1] = fmaf(a[j + 1], g[j + 1], uv); y1 = fmaf(w[j + 1], g[j + 1], y1);
            }
            float yp = y0 + y1;
            yp = dpp_xor1(yp);    // quad partial
            yp = dpp_xor2(yp);    // quad sum (all 4 lanes)
            yp = dpp_mir8(yp);    // + other quad's sum -> full 8-lane sum
            y4[e] = yp;
        }
        if (grp == 0)
            *reinterpret_cast<float4*>(&uS[cb + tq * 4]) =
                make_float4(y4[0], y4[1], y4[2], y4[3]);
    }

    __syncthreads();

    // ---- coalesced float4 writeout of y ----
    {
        float* ybase = y + ((size_t)b * DM + dp * 2) * LL;
#pragma unroll
        for (int k = 0; k < 4; ++k) {
            const int idx = tid + k * 256;
            const int r   = idx >> 9;
            const int t4  = (idx & 511) * 4;
            const int c   = t4 >> 7;
            const int tin = t4 & 127;
            const float4 v = *reinterpret_cast<const float4*>(&uS[r * RSTR + c * CPAD + tin]);
            *reinterpret_cast<float4*>(ybase + (size_t)r * LL + t4) = v;
        }
    }
}

extern "C" void kernel_launch(void* const* d_in, const int* in_sizes, int n_in,
                              void* d_out, int out_size, void* d_ws, size_t ws_size,
                              hipStream_t stream) {
    const float* u  = (const float*)d_in[0];
    const float* A  = (const float*)d_in[1];
    const float* Bv = (const float*)d_in[2];
    const float* Cv = (const float*)d_in[3];
    float* y = (float*)d_out;

    ssm_fused<<<BS * (DM / 2), 256, 0, stream>>>(u, A, Bv, Cv, y);
}

// Round 11
// 43.225 us; speedup vs baseline: 2.9305x; 1.5395x over previous
//
#include <hip/hip_runtime.h>

#define BS 4
#define DM 1024
#define LL 2048
#define NS 64
#define CC 32        // chunks
#define TT 64        // chunk length
#define PAD 68       // LDS row stride (elements): 136B -> <=2-way bank conflicts (free)

typedef __attribute__((ext_vector_type(8))) short bf8;     // 8 bf16 (4 VGPR)
typedef __attribute__((ext_vector_type(4))) float f32x4;   // mfma C/D

__device__ __forceinline__ unsigned short f2bf(float x) {  // fp32 -> bf16 RNE
    unsigned u = __float_as_uint(x);
    return (unsigned short)((u + 0x7FFFu + ((u >> 16) & 1u)) >> 16);
}

__device__ __forceinline__ bf8 ld_frag(const short* p) {   // 8 contiguous bf16 from LDS
    short4 a = *(const short4*)p;
    short4 b = *(const short4*)(p + 4);
    bf8 f;
    f[0]=a.x; f[1]=a.y; f[2]=a.z; f[3]=a.w;
    f[4]=b.x; f[5]=b.y; f[6]=b.z; f[7]=b.w;
    return f;
}

// stage one U chunk tile (64 d-rows x 64 t) fp32 global -> bf16 LDS [d][t], stride PAD
__device__ __forceinline__ void stage_u(const float* ubase, short* Ul, int tid) {
#pragma unroll
    for (int k = 0; k < 4; ++k) {
        const int idx = tid + k * 256;
        const int r   = idx >> 4;            // d-row 0..63
        const int t4  = (idx & 15) * 4;      // 16 float4 per row
        const float4 v = *(const float4*)(ubase + (size_t)r * LL + t4);
        short4 h = make_short4((short)f2bf(v.x), (short)f2bf(v.y),
                               (short)f2bf(v.z), (short)f2bf(v.w));
        *(short4*)&Ul[r * PAD + t4] = h;
    }
}

// ---------------- k1: Hloc = P @ U per (b, c, dtile)  [MFMA] ----------------
__global__ __launch_bounds__(256) void ssm_k1(const float* __restrict__ u,
                                              const float* __restrict__ A,
                                              const float* __restrict__ Bv,
                                              float* __restrict__ s) {
    __shared__ short Pl[64 * PAD];
    __shared__ short Ul[64 * PAD];
    const int tid = threadIdx.x;
    const int bx  = blockIdx.x;                 // 2048 = b(4) * c(32) * dt(16)
    const int dt  = bx & 15, c = (bx >> 4) & 31, b = bx >> 9;

    stage_u(u + ((size_t)(b * DM + dt * 64)) * LL + c * TT, Ul, tid);

    // P[i][sigma] = Bv_i * a_i^(63-sigma)
    {
        const int i = tid & 63, sq_ = tid >> 6, q = 3 - sq_, s0 = sq_ * 16;
        const float a  = A[i * (NS + 1)];
        const float bv = Bv[i];
        const float a2 = a*a, a4 = a2*a2, a8 = a4*a4, a16 = a8*a8, a32 = a16*a16;
        float p = bv * ((q & 1) ? a16 : 1.f) * ((q & 2) ? a32 : 1.f);  // bv * a^(16q)
#pragma unroll
        for (int jj = 15; jj >= 0; --jj) { Pl[i * PAD + s0 + jj] = (short)f2bf(p); p *= a; }
    }
    __syncthreads();

    const int w = tid >> 6, l = tid & 63;
    const int lm = l & 15, lk8 = (l >> 4) * 8;

    f32x4 acc[4];
#pragma unroll
    for (int n = 0; n < 4; ++n) acc[n] = (f32x4){0.f, 0.f, 0.f, 0.f};

    const bf8 aP0 = ld_frag(&Pl[(w * 16 + lm) * PAD + lk8]);        // k = 0..31
    const bf8 aP1 = ld_frag(&Pl[(w * 16 + lm) * PAD + 32 + lk8]);   // k = 32..63
#pragma unroll
    for (int n = 0; n < 4; ++n) {
        const bf8 b0 = ld_frag(&Ul[(n * 16 + lm) * PAD + lk8]);
        const bf8 b1 = ld_frag(&Ul[(n * 16 + lm) * PAD + 32 + lk8]);
        acc[n] = __builtin_amdgcn_mfma_f32_16x16x32_bf16(aP0, b0, acc[n], 0, 0, 0);
        acc[n] = __builtin_amdgcn_mfma_f32_16x16x32_bf16(aP1, b1, acc[n], 0, 0, 0);
    }

    // store Hloc fp32, layout s[((c*BS+b)*DM + d)*NS + i], i-contiguous float4
    const int i0 = w * 16 + (l >> 4) * 4;
#pragma unroll
    for (int n = 0; n < 4; ++n) {
        const int d = dt * 64 + n * 16 + lm;
        *(f32x4*)&s[(((size_t)c * BS + b) * DM + d) * NS + i0] = acc[n];
    }
}

// ---------------- combine: Hloc -> exclusive h_init (bf16)  [verified scan] ----------------
__global__ __launch_bounds__(256) void ssm_combine(const float* __restrict__ A,
                                                   const float* __restrict__ s_in,
                                                   unsigned short* __restrict__ h_out) {
    const int gid = blockIdx.x * 256 + threadIdx.x;   // B*D*N threads
    const int i = gid & 63;
    const int d = (gid >> 6) & (DM - 1);
    const int b = gid >> 16;

    const float a = A[i * (NS + 1)];
    float aT = a;                       // a^64
#pragma unroll
    for (int j = 0; j < 6; ++j) aT *= aT;

    const size_t base = ((size_t)b * DM + d) * NS + i;
    const size_t cstr = (size_t)BS * DM * NS;

    float v[CC];
#pragma unroll
    for (int c = 0; c < CC; ++c) v[c] = s_in[base + (size_t)c * cstr];

    float run = 0.f;
#pragma unroll
    for (int c = 0; c < CC; ++c) {
        h_out[base + (size_t)c * cstr] = f2bf(run);   // exclusive: h_init of chunk c
        run = fmaf(aT, run, v[c]);
    }
}

// ---------------- k3: Y = L@U + V@Hinit per (b, c, dtile)  [MFMA] ----------------
__global__ __launch_bounds__(256) void ssm_k3(const float* __restrict__ u,
                                              const float* __restrict__ A,
                                              const float* __restrict__ Bv,
                                              const float* __restrict__ Cv,
                                              const unsigned short* __restrict__ hinit,
                                              float* __restrict__ y) {
    __shared__ short LV[2 * 64 * PAD];  // phase1: fp32 scratch (64x68); phase2: L | V bf16
    __shared__ short Ul[64 * PAD];
    __shared__ short Hl[64 * PAD];
    __shared__ float kf[64];
    __shared__ float part[256];

    const int tid = threadIdx.x;
    const int bx  = blockIdx.x;
    const int dt  = bx & 15, c = (bx >> 4) & 31, b = bx >> 9;

    const int   im = tid & 63;
    const float a  = A[im * (NS + 1)];
    const float cv = Cv[im];
    const float wv = Bv[im] * cv;
    const float a2 = a*a, a4 = a2*a2, a8 = a4*a4, a16 = a8*a8, a32 = a16*a16;

    stage_u(u + ((size_t)(b * DM + dt * 64)) * LL + c * TT, Ul, tid);

    // stage Hinit (64 d x 64 i bf16) -> LDS [d][i]
    {
        const unsigned short* hb = hinit + (((size_t)c * BS + b) * DM + dt * 64) * NS;
#pragma unroll
        for (int k = 0; k < 2; ++k) {
            const int idx = tid + k * 256;
            const int r   = idx >> 3;
            const int i16 = (idx & 7) * 8;
            const uint4 vv = *(const uint4*)(hb + (size_t)r * NS + i16);
            *(uint2*)&Hl[r * PAD + i16]     = make_uint2(vv.x, vv.y);
            *(uint2*)&Hl[r * PAD + i16 + 4] = make_uint2(vv.z, vv.w);
        }
    }

    // scratch[delta][i] = w_i * a_i^delta  (for kernel taps)
    {
        float* scr = (float*)LV;
        const int dq = tid >> 6, D0 = dq * 16;
        float p = wv * ((dq & 1) ? a16 : 1.f) * ((dq & 2) ? a32 : 1.f);  // w * a^(16 dq)
#pragma unroll
        for (int dd = 0; dd < 16; ++dd) { scr[(D0 + dd) * PAD + im] = p; p *= a; }
    }
    __syncthreads();
    {   // reduce over i: k[delta] = sum_i scr[delta][i]
        float* scr = (float*)LV;
        const int Dl = tid & 63, q = tid >> 6;
        float ssum = 0.f;
#pragma unroll
        for (int ii = 0; ii < 16; ++ii) ssum += scr[Dl * PAD + q * 16 + ii];
        part[tid] = ssum;
    }
    __syncthreads();
    if (tid < 64) kf[tid] = part[tid] + part[tid + 64] + part[tid + 128] + part[tid + 192];
    __syncthreads();

    // fill L (lower-tri Toeplitz of kf) and V[r][i] = C_i a_i^(r+1), overwriting scratch
    {
        short* Ll = LV;
        const int r = tid >> 2, sb = (tid & 3) * 16;
#pragma unroll
        for (int s2 = 0; s2 < 16; ++s2) {
            const int sc = sb + s2;
            Ll[r * PAD + sc] = (r >= sc) ? (short)f2bf(kf[r - sc]) : (short)0;
        }
        short* Vl = LV + 64 * PAD;
        const int rq = tid >> 6, r0 = rq * 16;
        float p = cv * a * ((rq & 1) ? a16 : 1.f) * ((rq & 2) ? a32 : 1.f);  // C a^(16rq+1)
#pragma unroll
        for (int rr = 0; rr < 16; ++rr) { Vl[(r0 + rr) * PAD + im] = (short)f2bf(p); p *= a; }
    }
    __syncthreads();

    // MFMA: wave w owns m-tile w (rows t), 4 n-tiles (cols d)
    const int w = tid >> 6, l = tid & 63;
    const int lm = l & 15, lk8 = (l >> 4) * 8;
    const short* Ll = LV;
    const short* Vl = LV + 64 * PAD;

    f32x4 acc[4];
#pragma unroll
    for (int n = 0; n < 4; ++n) acc[n] = (f32x4){0.f, 0.f, 0.f, 0.f};

    const bf8 aL0 = ld_frag(&Ll[(w * 16 + lm) * PAD + lk8]);
    const bf8 aL1 = ld_frag(&Ll[(w * 16 + lm) * PAD + 32 + lk8]);
    const bf8 aV0 = ld_frag(&Vl[(w * 16 + lm) * PAD + lk8]);
    const bf8 aV1 = ld_frag(&Vl[(w * 16 + lm) * PAD + 32 + lk8]);
#pragma unroll
    for (int n = 0; n < 4; ++n) {
        const bf8 bU0 = ld_frag(&Ul[(n * 16 + lm) * PAD + lk8]);
        const bf8 bU1 = ld_frag(&Ul[(n * 16 + lm) * PAD + 32 + lk8]);
        const bf8 bH0 = ld_frag(&Hl[(n * 16 + lm) * PAD + lk8]);
        const bf8 bH1 = ld_frag(&Hl[(n * 16 + lm) * PAD + 32 + lk8]);
        acc[n] = __builtin_amdgcn_mfma_f32_16x16x32_bf16(aL0, bU0, acc[n], 0, 0, 0);
        acc[n] = __builtin_amdgcn_mfma_f32_16x16x32_bf16(aL1, bU1, acc[n], 0, 0, 0);
        acc[n] = __builtin_amdgcn_mfma_f32_16x16x32_bf16(aV0, bH0, acc[n], 0, 0, 0);
        acc[n] = __builtin_amdgcn_mfma_f32_16x16x32_bf16(aV1, bH1, acc[n], 0, 0, 0);
    }

    // store y fp32: t = c*64 + w*16 + (l>>4)*4 + r (contiguous), d = dt*64 + n*16 + lm
    const int t0 = c * TT + w * 16 + (l >> 4) * 4;
#pragma unroll
    for (int n = 0; n < 4; ++n) {
        const int d = dt * 64 + n * 16 + lm;
        *(f32x4*)&y[((size_t)b * DM + d) * LL + t0] = acc[n];
    }
}

extern "C" void kernel_launch(void* const* d_in, const int* in_sizes, int n_in,
                              void* d_out, int out_size, void* d_ws, size_t ws_size,
                              hipStream_t stream) {
    const float* u  = (const float*)d_in[0];
    const float* A  = (const float*)d_in[1];
    const float* Bv = (const float*)d_in[2];
    const float* Cv = (const float*)d_in[3];
    float* y = (float*)d_out;

    float*          s = (float*)d_ws;                                  // 32 MB fp32 Hloc
    unsigned short* h = (unsigned short*)((char*)d_ws + 33554432);     // 16 MB bf16 h_init

    const int nblk = BS * CC * (DM / 64);   // 2048
    ssm_k1<<<nblk, 256, 0, stream>>>(u, A, Bv, s);
    ssm_combine<<<(BS * DM * NS) / 256, 256, 0, stream>>>(A, s, h);
    ssm_k3<<<nblk, 256, 0, stream>>>(u, A, Bv, Cv, h, y);
}

// Round 12
// 24.767 us; speedup vs baseline: 5.1146x; 1.7453x over previous
//
#include <hip/hip_runtime.h>

#define BS 4
#define DM 1024
#define LL 2048
#define NS 64
#define CC 32        // chunks
#define TT 64        // chunk length
#define PAD 68       // LDS row stride for 64-wide mats (verified conflict-light)
#define UPAD 2060    // U row stride (elements): dword stride 1030 = 32*32+6 -> spread banks
#define DT 16        // d-rows per block

typedef __attribute__((ext_vector_type(8))) short bf8;     // 8 bf16 (4 VGPR)
typedef __attribute__((ext_vector_type(4))) float f32x4;   // mfma C/D

__device__ __forceinline__ unsigned short f2bf(float x) {  // fp32 -> bf16 RNE
    unsigned u = __float_as_uint(x);
    return (unsigned short)((u + 0x7FFFu + ((u >> 16) & 1u)) >> 16);
}

__device__ __forceinline__ bf8 ld_frag(const short* p) {   // 8 contiguous bf16 from LDS
    short4 a = *(const short4*)p;
    short4 b = *(const short4*)(p + 4);
    bf8 f;
    f[0]=a.x; f[1]=a.y; f[2]=a.z; f[3]=a.w;
    f[4]=b.x; f[5]=b.y; f[6]=b.z; f[7]=b.w;
    return f;
}

// One kernel, one pass: 256 blocks (b x 16-d tile) x 512 thr (8 waves).
// Waves 0-3: scan (Hloc = P@U, h_run in AGPR-free f32x4). Waves 4-7: Y = L@U + V@h_init.
__global__ __launch_bounds__(512, 2) void ssm_one(const float* __restrict__ u,
                                                  const float* __restrict__ A,
                                                  const float* __restrict__ Bv,
                                                  const float* __restrict__ Cv,
                                                  float* __restrict__ y) {
    __shared__ short Ul[DT * UPAD];     // 65920 B: u row-block, bf16
    __shared__ short Pl[64 * PAD];      // 8704 B
    __shared__ short LV[2 * 64 * PAD];  // 17408 B: fp32 scratch, then L | V bf16
    __shared__ short Hl[DT * PAD];      // 2176 B: h_init handoff (d x i)
    __shared__ float kf[64];
    __shared__ float part[256];

    const int tid = threadIdx.x;
    const int bx  = blockIdx.x;         // 256 = b(4) * dt(64)
    const int dt  = bx & 63, b = bx >> 6;
    const int wid = tid >> 6;
    const int l   = tid & 63;
    const int lm  = l & 15, lq = l >> 4, lk8 = (l >> 4) * 8;

    // ---- stage U: 16 rows x 2048 t, fp32 -> bf16, one full row per iteration ----
    {
        const float* ubase = u + ((size_t)(b * DM + dt * DT)) * LL;
#pragma unroll
        for (int k = 0; k < DT; ++k) {
            const int t4 = tid * 4;                       // 512 thr x 4 = 2048
            const float4 v = *(const float4*)(ubase + (size_t)k * LL + t4);
            short4 h = make_short4((short)f2bf(v.x), (short)f2bf(v.y),
                                   (short)f2bf(v.z), (short)f2bf(v.w));
            *(short4*)&Ul[k * UPAD + t4] = h;
        }
    }

    // ---- builders (concurrent): wid<4 -> P;  wid>=4 -> kernel-tap scratch ----
    if (wid < 4) {
        // P[i][sigma] = Bv_i * a_i^(63-sigma)   (verbatim from verified k1)
        const int i = tid & 63, sq_ = tid >> 6, q = 3 - sq_, s0 = sq_ * 16;
        const float a  = A[i * (NS + 1)];
        const float bv = Bv[i];
        const float a2 = a*a, a4 = a2*a2, a8 = a4*a4, a16 = a8*a8, a32 = a16*a16;
        float p = bv * ((q & 1) ? a16 : 1.f) * ((q & 2) ? a32 : 1.f);
#pragma unroll
        for (int jj = 15; jj >= 0; --jj) { Pl[i * PAD + s0 + jj] = (short)f2bf(p); p *= a; }
    } else {
        // scratch[delta][i] = w_i * a_i^delta   (verbatim from verified k3)
        const int t2 = tid - 256;
        float* scr = (float*)LV;
        const int im = t2 & 63, dq = t2 >> 6, D0 = dq * 16;
        const float a  = A[im * (NS + 1)];
        const float wv = Bv[im] * Cv[im];
        const float a2 = a*a, a4 = a2*a2, a8 = a4*a4, a16 = a8*a8, a32 = a16*a16;
        float p = wv * ((dq & 1) ? a16 : 1.f) * ((dq & 2) ? a32 : 1.f);
#pragma unroll
        for (int dd = 0; dd < 16; ++dd) { scr[(D0 + dd) * PAD + im] = p; p *= a; }
    }
    __syncthreads();
    if (wid >= 4) {   // k[delta] = sum_i scratch[delta][i]
        const int t2 = tid - 256;
        float* scr = (float*)LV;
        const int Dl = t2 & 63, q = t2 >> 6;
        float ssum = 0.f;
#pragma unroll
        for (int ii = 0; ii < 16; ++ii) ssum += scr[Dl * PAD + q * 16 + ii];
        part[t2] = ssum;
    }
    __syncthreads();
    if (tid >= 256 && tid < 320) {
        const int t2 = tid - 256;
        kf[t2] = part[t2] + part[t2 + 64] + part[t2 + 128] + part[t2 + 192];
    }
    __syncthreads();
    if (wid >= 4) {
        const int t2 = tid - 256;
        // L (lower-tri Toeplitz of kf), overwrites scratch
        short* Ll = LV;
        const int r = t2 >> 2, sb = (t2 & 3) * 16;
#pragma unroll
        for (int s2 = 0; s2 < 16; ++s2) {
            const int sc = sb + s2;
            Ll[r * PAD + sc] = (r >= sc) ? (short)f2bf(kf[r - sc]) : (short)0;
        }
        // V[r][i] = C_i * a_i^(r+1)
        short* Vl = LV + 64 * PAD;
        const int im = t2 & 63, rq = t2 >> 6, r0 = rq * 16;
        const float a  = A[im * (NS + 1)];
        const float cv = Cv[im];
        const float a2 = a*a, a4 = a2*a2, a8 = a4*a4, a16 = a8*a8, a32 = a16*a16;
        float p = cv * a * ((rq & 1) ? a16 : 1.f) * ((rq & 2) ? a32 : 1.f);
#pragma unroll
        for (int rr = 0; rr < 16; ++rr) { Vl[(r0 + rr) * PAD + im] = (short)f2bf(p); p *= a; }
    }
    __syncthreads();

    // ---- per-wave invariant fragments + scan state ----
    bf8 fA0, fA1, fB0, fB1;
    float aT[4];
    f32x4 hrun = (f32x4){0.f, 0.f, 0.f, 0.f};
    if (wid < 4) {
        fA0 = ld_frag(&Pl[(wid * 16 + lm) * PAD + lk8]);
        fA1 = ld_frag(&Pl[(wid * 16 + lm) * PAD + 32 + lk8]);
        fB0 = fA0; fB1 = fA1;   // unused
#pragma unroll
        for (int r = 0; r < 4; ++r) {       // aT = a_i^64 for my 4 acc rows
            const int i = wid * 16 + lq * 4 + r;
            float x = A[i * (NS + 1)];
#pragma unroll
            for (int q = 0; q < 6; ++q) x = x * x;
            aT[r] = x;
        }
    } else {
        const int wt = wid - 4;
        fA0 = ld_frag(&LV[(wt * 16 + lm) * PAD + lk8]);              // L
        fA1 = ld_frag(&LV[(wt * 16 + lm) * PAD + 32 + lk8]);
        fB0 = ld_frag(&LV[64 * PAD + (wt * 16 + lm) * PAD + lk8]);   // V
        fB1 = ld_frag(&LV[64 * PAD + (wt * 16 + lm) * PAD + 32 + lk8]);
        aT[0] = aT[1] = aT[2] = aT[3] = 0.f;
    }

    // ---- chunk loop: scan waves produce h_init; Y waves consume it same-iteration ----
    for (int c = 0; c < CC; ++c) {
        if (wid < 4) {   // h_init(c) = hrun (exclusive), bf16 -> Hl[d][i]
            const int i0 = wid * 16 + lq * 4;
            short4 hh = make_short4((short)f2bf(hrun[0]), (short)f2bf(hrun[1]),
                                    (short)f2bf(hrun[2]), (short)f2bf(hrun[3]));
            *(short4*)&Hl[lm * PAD + i0] = hh;
        }
        __syncthreads();

        const int tb = c * TT;
        const bf8 bU0 = ld_frag(&Ul[lm * UPAD + tb + lk8]);
        const bf8 bU1 = ld_frag(&Ul[lm * UPAD + tb + 32 + lk8]);

        if (wid < 4) {
            f32x4 hl = (f32x4){0.f, 0.f, 0.f, 0.f};
            hl = __builtin_amdgcn_mfma_f32_16x16x32_bf16(fA0, bU0, hl, 0, 0, 0);
            hl = __builtin_amdgcn_mfma_f32_16x16x32_bf16(fA1, bU1, hl, 0, 0, 0);
#pragma unroll
            for (int r = 0; r < 4; ++r) hrun[r] = fmaf(aT[r], hrun[r], hl[r]);
        } else {
            const bf8 bH0 = ld_frag(&Hl[lm * PAD + lk8]);
            const bf8 bH1 = ld_frag(&Hl[lm * PAD + 32 + lk8]);
            f32x4 yac = (f32x4){0.f, 0.f, 0.f, 0.f};
            yac = __builtin_amdgcn_mfma_f32_16x16x32_bf16(fA0, bU0, yac, 0, 0, 0);
            yac = __builtin_amdgcn_mfma_f32_16x16x32_bf16(fA1, bU1, yac, 0, 0, 0);
            yac = __builtin_amdgcn_mfma_f32_16x16x32_bf16(fB0, bH0, yac, 0, 0, 0);
            yac = __builtin_amdgcn_mfma_f32_16x16x32_bf16(fB1, bH1, yac, 0, 0, 0);
            const int wt = wid - 4;
            const int t0 = tb + wt * 16 + lq * 4;     // rows of C = t (contiguous 4)
            *(f32x4*)&y[((size_t)(b * DM + dt * DT + lm)) * LL + t0] = yac;
        }
        __syncthreads();
    }
}

extern "C" void kernel_launch(void* const* d_in, const int* in_sizes, int n_in,
                              void* d_out, int out_size, void* d_ws, size_t ws_size,
                              hipStream_t stream) {
    const float* u  = (const float*)d_in[0];
    const float* A  = (const float*)d_in[1];
    const float* Bv = (const float*)d_in[2];
    const float* Cv = (const float*)d_in[3];
    float* y = (float*)d_out;

    ssm_one<<<BS * (DM / DT), 512, 0, stream>>>(u, A, Bv, Cv, y);
}